// Round 10
// baseline (331.872 us; speedup 1.0000x reference)
//
#include <hip/hip_runtime.h>

// MaskedSelfAttention: B=4, S=4096, D=1024, H=128. fp32 in/out, bf16 MFMA compute.
// v17: flash restructured 4x32q -> 8 waves x 16q (512-thread blocks). Session
// law: occupancy is wave-arithmetic-capped (invariant to grid 476/896; v16
// C=5 = 15.5% again); the only occupancy doubling all session was v9's VGPR
// halving. Halve per-wave state structurally: o[8] (32 regs), s[4] (16),
// qf[4] (16) -> fits (512,4)'s 128-VGPR cap without clamp-spill; 16 waves/CU
// at 2 blocks/CU (vs 8). Same K-LDS dbuf staging (now 8-wave-shared), same
// per-iter math, half softmax VALU per wave. C=8 -> 576 blocks (>=512
// resident slots). qkv/prep/mergeN = v13-exact (best total 205.4); all
// partials to pex (v13 merge form). ws 31.8MiB (v9 proved >=35.5 fits).

typedef __bf16 bf16x8 __attribute__((ext_vector_type(8)));
typedef __bf16 bf16x4 __attribute__((ext_vector_type(4)));
typedef __bf16 bf16x2 __attribute__((ext_vector_type(2)));
typedef float  f32x4  __attribute__((ext_vector_type(4)));

#define MFMA16(a, b, c) __builtin_amdgcn_mfma_f32_16x16x32_bf16(a, b, c, 0, 0, 0)
#define EXP2F(x) __builtin_amdgcn_exp2f(x)

__device__ __forceinline__ void gld_lds16(const void* g, void* l)
{
    __builtin_amdgcn_global_load_lds(
        (const __attribute__((address_space(1))) void*)g,
        (__attribute__((address_space(3))) void*)l, 16, 0, 0);
}

// ---------------------------------------------------------------- prep_w ----
__global__ __launch_bounds__(256) void prep_w(
    const float* __restrict__ Wq, const float* __restrict__ Wk,
    const float* __restrict__ Wv, __bf16* __restrict__ Wb)
{
    int i = (blockIdx.x * 256 + threadIdx.x) * 4;
    int row = i >> 10;
    const float* W = (row < 128) ? Wq : (row < 256) ? Wk : Wv;
    float4 v = *(const float4*)&W[(size_t)(row & 127) * 1024 + (i & 1023)];
    bf16x4 pk = {(__bf16)v.x, (__bf16)v.y, (__bf16)v.z, (__bf16)v.w};
    *(bf16x4*)&Wb[i] = pk;
}

// -------------------------------------------------------------- qkv_gemm ----
// v13-exact (measured 62us): 64x128 tile, BK=64, staging via global_load_lds
// only (A f32 + B bf16, 64KB dbuf), both-sides XOR swizzle, one barrier per
// iter, XCD slab grouping.
__global__ __launch_bounds__(256, 2) void qkv_gemm(
    const float* __restrict__ x, const __bf16* __restrict__ Wb,
    const float* __restrict__ bq, const float* __restrict__ bk,
    const float* __restrict__ bv,
    __bf16* __restrict__ Qb, __bf16* __restrict__ Kb, __bf16* __restrict__ Vt)
{
    __shared__ __align__(16) float  As[2][64][64];    // 32 KiB
    __shared__ __align__(16) __bf16 Bs[2][128][64];   // 32 KiB

    const int tid   = threadIdx.x;
    const int bx    = blockIdx.x;
    const int xcd   = bx & 7, w8 = bx >> 3;   // 96 blocks per xcd
    const int slab  = xcd * 32 + w8 / 3;      // 0..255
    const int which = w8 % 3;                 // 0=Q 1=K 2=V
    const int m0    = slab * 64;
    const int n0    = which * 128;
    const int lane = tid & 63, wid = tid >> 6;
    const int quad = lane >> 4, l16 = lane & 15;
    const int wm = (wid >> 1) * 32, wn = (wid & 1) * 64;

    const f32x4 fzero = {0.f, 0.f, 0.f, 0.f};
    f32x4 acc[2][4];
#pragma unroll
    for (int i = 0; i < 2; ++i)
#pragma unroll
        for (int j = 0; j < 4; ++j) acc[i][j] = fzero;

    const int rlA = lane >> 4, cA = lane & 15;        // A: 4 rows/inst
    const int rlB = lane >> 3, cB = lane & 7;         // B: 8 rows/inst

#define STAGE(bufi, kk)                                                        \
    {                                                                          \
        _Pragma("unroll")                                                      \
        for (int i = 0; i < 4; ++i) {                                          \
            int R  = wid * 16 + i * 4;                                         \
            int sw = (i & 1) * 4 + rlA;              /* (R+rlA)&7 */           \
            gld_lds16(&x[(size_t)(m0 + R + rlA) * 1024 + (kk) + ((cA ^ sw) * 4)],\
                      &As[bufi][R][0]);                                        \
        }                                                                      \
        _Pragma("unroll")                                                      \
        for (int i = 0; i < 4; ++i) {                                          \
            int R = wid * 32 + i * 8;                                          \
            gld_lds16(&Wb[(size_t)(n0 + R + rlB) * 1024 + (kk) + ((cB ^ rlB) * 8)],\
                      &Bs[bufi][R][0]);                                        \
        }                                                                      \
    }

    STAGE(0, 0);
    __syncthreads();

    const int sA = l16 & 7;
    for (int t = 0; t < 16; ++t) {
        const int buf = t & 1;
        if (t < 15) STAGE(buf ^ 1, (t + 1) * 64);     // DMA flies under MFMA
#pragma unroll
        for (int ks = 0; ks < 2; ++ks) {
            bf16x8 a[2], bb[4];
#pragma unroll
            for (int mt = 0; mt < 2; ++mt) {
                int r  = wm + mt * 16 + l16;
                int c0 = ks * 8 + quad * 2;
                f32x4 a0 = *(const f32x4*)&As[buf][r][(c0 ^ sA) * 4];
                f32x4 a1 = *(const f32x4*)&As[buf][r][((c0 + 1) ^ sA) * 4];
                a[mt] = (bf16x8){(__bf16)a0[0], (__bf16)a0[1], (__bf16)a0[2], (__bf16)a0[3],
                                 (__bf16)a1[0], (__bf16)a1[1], (__bf16)a1[2], (__bf16)a1[3]};
            }
#pragma unroll
            for (int nt = 0; nt < 4; ++nt) {
                int r  = wn + nt * 16 + l16;
                int cc = (ks * 4 + quad) ^ sA;
                bb[nt] = *(const bf16x8*)&Bs[buf][r][cc * 8];
            }
#pragma unroll
            for (int mt = 0; mt < 2; ++mt)
#pragma unroll
                for (int nt = 0; nt < 4; ++nt)
                    acc[mt][nt] = MFMA16(a[mt], bb[nt], acc[mt][nt]);
        }
        __syncthreads();   // drains tile t+1's DMA (vmcnt 0) + barrier
    }

    const float* bias = (which == 0) ? bq : (which == 1) ? bk : bv;
    if (which < 2) {
        __bf16* dst = (which == 0) ? Qb : Kb;
#pragma unroll
        for (int nt = 0; nt < 4; ++nt) {
            int col = wn + nt * 16 + l16;
            float bvv = bias[col];
#pragma unroll
            for (int mt = 0; mt < 2; ++mt)
#pragma unroll
                for (int r = 0; r < 4; ++r) {
                    int row = m0 + wm + mt * 16 + quad * 4 + r;
                    dst[(size_t)row * 128 + col] = (__bf16)(acc[mt][nt][r] + bvv);
                }
        }
    } else {
#pragma unroll
        for (int nt = 0; nt < 4; ++nt) {
            int col = wn + nt * 16 + l16;               // head index
            float bvv = bias[col];
#pragma unroll
            for (int mt = 0; mt < 2; ++mt) {
                int row = m0 + wm + mt * 16 + quad * 4;
                int bb_ = row >> 12, s = row & 4095;
                bf16x4 pk = {(__bf16)(acc[mt][nt][0] + bvv),
                             (__bf16)(acc[mt][nt][1] + bvv),
                             (__bf16)(acc[mt][nt][2] + bvv),
                             (__bf16)(acc[mt][nt][3] + bvv)};
                *(bf16x4*)&Vt[((size_t)(bb_ * 128 + col)) * 4096 + s] = pk;
            }
        }
    }
#undef STAGE
}

// -------------------------------------------------------------- flash_attn --
// v17: 512 threads = 8 waves x 16 q-rows (128-q tile). K LDS-staged dbuf +
// XOR swizzle shared by all 8 waves; V direct+prefetch; per-wave plT.
// Per-wave state halved vs v13 -> (512,4) cap 128 VGPR fits -> 16 waves/CU.
// C=8 -> 576 blocks. All partials to pex (v13 merge form).
__global__ __launch_bounds__(512, 4) void flash_attn(
    const __bf16* __restrict__ Qb, const __bf16* __restrict__ Kb,
    const __bf16* __restrict__ Vt, const int* __restrict__ mask,
    float* __restrict__ ml, __bf16* __restrict__ pex)
{
    __shared__ __align__(16) char smem[51200];
    __bf16 (*Ks)[64][128] = (__bf16(*)[64][128])smem;            // 32 KiB dbuf
    __bf16 (*plT)[16][72] = (__bf16(*)[16][72])(smem + 32768);   // 18 KiB (8 waves)
    __bf16 (*OL)[136]     = (__bf16(*)[136])smem;                // epilogue overlay

    // ---- block -> (T, b, j): n(T)=ceil((T+1)/4) chunks of <=8 key-iters ----
    int ii = blockIdx.x, T = 0, n, cum = 0;
    for (;; ++T) {
        n = (T + 4) / 4;
        if (ii < 4 * n) break;
        ii -= 4 * n;
        cum += n;
    }
    const int b  = ii / n;
    const int j  = ii % n;
    const int nk = 2 * (T + 1);
    const int t0 = j * 8;
    const int t1 = (nk < t0 + 8) ? nk : (t0 + 8);
    const int r0 = T * 128;
    const int slot = b * 144 + cum + j;      // ml/pex slot id (576 total)

    const int tid = threadIdx.x, wid = tid >> 6, lane = tid & 63;
    const int quad = lane >> 4, l16 = lane & 15;
    const int qw = r0 + wid * 16;                      // wave's q base (16 rows)
    const size_t sb = (size_t)b * 4096;
    const float qs = 0.08838834764831845f * 1.4426950408889634f; // scale*log2e

    const int rlK = lane >> 4, cK = lane & 15;         // K staging map
    const int sK  = l16 & 7;                           // K read swizzle

#define STAGE_K(bufi, kk)                                                      \
    {                                                                          \
        _Pragma("unroll")                                                      \
        for (int i_ = 0; i_ < 2; ++i_) {                                       \
            int R_   = wid * 8 + i_ * 4;                                       \
            int row_ = R_ + rlK;                                               \
            gld_lds16(&Kb[(sb + (kk) + row_) * 128 + ((cK ^ (row_ & 7)) * 8)], \
                      &Ks[bufi][R_][0]);                                       \
        }                                                                      \
    }

    bf16x8 qf[4];                                      // Q B-frags, scale folded
#pragma unroll
    for (int ks = 0; ks < 4; ++ks) {
        qf[ks] = *(const bf16x8*)
            &Qb[(sb + qw + l16) * 128 + ks * 32 + quad * 8];
#pragma unroll
        for (int e = 0; e < 8; ++e)
            qf[ks][e] = (__bf16)((float)qf[ks][e] * qs);
    }

    float mi = -1e30f, li = 0.f;
    const f32x4 fzero = {0.f, 0.f, 0.f, 0.f};
    f32x4 o[8];                                        // O^T: 8 head-frags x 16q
#pragma unroll
    for (int hf = 0; hf < 8; ++hf) o[hf] = fzero;

    const __bf16* vb = Vt + ((size_t)b * 128 + l16) * 4096 + quad * 8;

    STAGE_K(0, t0 * 64);
    __syncthreads();

    for (int t = t0; t < t1; ++t) {
        const int k0 = t * 64;
        const int buf = (t - t0) & 1;
        if (t + 1 < t1) STAGE_K(buf ^ 1, k0 + 64);     // DMA flies under compute
        const int mv = mask[sb + k0 + lane];

        // ---- S^T = K Q^T from LDS: rows=keys(64, 4 mf), cols=q(16) ----
        f32x4 s[4];
#pragma unroll
        for (int mf = 0; mf < 4; ++mf) s[mf] = fzero;
        __builtin_amdgcn_s_setprio(1);
#pragma unroll
        for (int ks = 0; ks < 4; ++ks) {
            bf16x8 a[4];
#pragma unroll
            for (int mf = 0; mf < 4; ++mf)
                a[mf] = *(const bf16x8*)
                    &Ks[buf][mf * 16 + l16][((ks * 4 + quad) ^ sK) * 8];
#pragma unroll
            for (int mf = 0; mf < 4; ++mf)
                s[mf] = MFMA16(a[mf], qf[ks], s[mf]);
        }
        __builtin_amdgcn_s_setprio(0);
        // prefetch PV first half's V frags above the softmax (hides L2 latency)
        bf16x8 va0[8];
#pragma unroll
        for (int hf = 0; hf < 8; ++hf)
            va0[hf] = *(const bf16x8*)&vb[(size_t)(hf * 16) * 4096 + k0];

        // ---- masking (C-layout: key = mf*16+quad*4+r, q = qw+l16) ----
        unsigned long long mb = __ballot(mv != 0);
        if (mb != ~0ull || k0 + 63 > qw) {
            const int q = qw + l16;
#pragma unroll
            for (int mf = 0; mf < 4; ++mf)
#pragma unroll
                for (int r = 0; r < 4; ++r) {
                    int kl = mf * 16 + quad * 4 + r;
                    bool ok = ((mb >> kl) & 1) && (k0 + kl <= q);
                    s[mf][r] = ok ? s[mf][r] : -1e30f;
                }
        }
        // ---- online softmax per q (log2 domain; reduce over quads) ----
        {
            float mx = s[0][0];
#pragma unroll
            for (int mf = 0; mf < 4; ++mf)
#pragma unroll
                for (int r = 0; r < 4; ++r) mx = fmaxf(mx, s[mf][r]);
            mx = fmaxf(mx, __shfl_xor(mx, 16));
            mx = fmaxf(mx, __shfl_xor(mx, 32));
            float mnew  = fmaxf(mi, mx);
            float alpha = EXP2F(mi - mnew);
            float rs = 0.f;
#pragma unroll
            for (int mf = 0; mf < 4; ++mf)
#pragma unroll
                for (int r = 0; r < 4; ++r) {
                    float sv = s[mf][r];
                    float p = (sv < -5e29f) ? 0.f : EXP2F(sv - mnew);
                    s[mf][r] = p;
                    rs += p;
                }
            rs += __shfl_xor(rs, 16);
            rs += __shfl_xor(rs, 32);
            li = li * alpha + rs;
            mi = mnew;
#pragma unroll
            for (int hf = 0; hf < 8; ++hf) {
                o[hf][0] *= alpha; o[hf][1] *= alpha;
                o[hf][2] *= alpha; o[hf][3] *= alpha;
            }
            // pack P (consecutive keys in-lane) -> b32 LDS writes
#pragma unroll
            for (int mf = 0; mf < 4; ++mf) {
                bf16x2 w0 = {(__bf16)s[mf][0], (__bf16)s[mf][1]};
                bf16x2 w1 = {(__bf16)s[mf][2], (__bf16)s[mf][3]};
                *(bf16x2*)&plT[wid][l16][mf * 16 + quad * 4]     = w0;
                *(bf16x2*)&plT[wid][l16][mf * 16 + quad * 4 + 2] = w1;
            }
        }
        asm volatile("s_waitcnt lgkmcnt(0)" ::: "memory"); // per-wave DS order
        // ---- O^T += V^T P^T (V frags straight from global) ----
        bf16x8 pb0 = *(const bf16x8*)&plT[wid][l16][quad * 8];
        bf16x8 pb1 = *(const bf16x8*)&plT[wid][l16][32 + quad * 8];
        bf16x8 va1[8];
#pragma unroll
        for (int hf = 0; hf < 8; ++hf)
            va1[hf] = *(const bf16x8*)&vb[(size_t)(hf * 16) * 4096 + k0 + 32];
        __builtin_amdgcn_s_setprio(1);
#pragma unroll
        for (int hf = 0; hf < 8; ++hf)
            o[hf] = MFMA16(va0[hf], pb0, o[hf]);
#pragma unroll
        for (int hf = 0; hf < 8; ++hf)
            o[hf] = MFMA16(va1[hf], pb1, o[hf]);
        __builtin_amdgcn_s_setprio(0);
        __syncthreads();   // drains next-tile K DMA; guards Ks[buf] reuse
    }

    // ---- epilogue: transpose O^T via LDS (overlay), bf16 partial store ----
    float inv = (li > 0.f) ? 1.0f / li : 0.f;
    {
        int ql = wid * 16 + l16;
#pragma unroll
        for (int hf = 0; hf < 8; ++hf) {
            int hd = hf * 16 + quad * 4;
            bf16x2 w0 = {(__bf16)(o[hf][0] * inv), (__bf16)(o[hf][1] * inv)};
            bf16x2 w1 = {(__bf16)(o[hf][2] * inv), (__bf16)(o[hf][3] * inv)};
            *(bf16x2*)&OL[ql][hd]     = w0;
            *(bf16x2*)&OL[ql][hd + 2] = w1;
        }
        if (quad == 0) {
            size_t base = ((size_t)slot * 128 + ql) * 2;
            ml[base]     = mi;
            ml[base + 1] = li;
        }
    }
    __syncthreads();
    __bf16* dst = pex + (size_t)slot * 16384;
    {
        int qrow = tid >> 2, cb2 = (tid & 3) * 32;
#pragma unroll
        for (int i = 0; i < 4; ++i) {
            bf16x8 v = *(const bf16x8*)&OL[qrow][cb2 + i * 8];
            *(bf16x8*)&dst[(size_t)qrow * 128 + cb2 + i * 8] = v;
        }
    }
#undef STAGE_K
}

// ----------------------------------------------------------------- mergeN ---
// v13 form, C=8: grid (32,4,4) = 512 blocks; each block: 32 q-rows x 128
// heads of one (b,T) tile. All partials in pex -> pure streaming, no LDS,
// no barrier.
__global__ __launch_bounds__(256) void mergeN(
    float* __restrict__ out, const float* __restrict__ ml,
    const __bf16* __restrict__ pex)
{
    const int T = blockIdx.x, b = blockIdx.y, z = blockIdx.z;
    int cum = 0;
    for (int tt = 0; tt < T; ++tt) cum += (tt + 4) / 4;
    const int n  = (T + 4) / 4;
    const int r0 = T * 128;
    const size_t sb = (size_t)b * 4096;
    const int ql = z * 32 + (threadIdx.x >> 3);
    const int ch = (threadIdx.x & 7) * 16;
    const int slot0 = b * 144 + cum;

    float mm = -1e30f;
    for (int jj = 0; jj < n; ++jj)
        mm = fmaxf(mm, ml[((size_t)(slot0 + jj) * 128 + ql) * 2]);

    float acc[16];
#pragma unroll
    for (int k = 0; k < 16; ++k) acc[k] = 0.f;
    float den = 0.f;
    for (int jj = 0; jj < n; ++jj) {
        size_t base = ((size_t)(slot0 + jj) * 128 + ql) * 2;
        float m = ml[base], l = ml[base + 1];
        float w = (l > 0.f) ? EXP2F(m - mm) * l : 0.f;
        den += w;
        const __bf16* p = pex + (size_t)(slot0 + jj) * 16384
                        + (size_t)ql * 128 + ch;
        bf16x8 v0 = *(const bf16x8*)&p[0];
        bf16x8 v1 = *(const bf16x8*)&p[8];
#pragma unroll
        for (int e = 0; e < 8; ++e) {
            acc[e]     += w * (float)v0[e];
            acc[8 + e] += w * (float)v1[e];
        }
    }
    float sc = (den > 0.f) ? 1.0f / den : 0.f;
    float* op = &out[(sb + r0 + ql) * 128 + ch];
#pragma unroll
    for (int q2 = 0; q2 < 4; ++q2) {
        float4 v = {acc[q2 * 4 + 0] * sc, acc[q2 * 4 + 1] * sc,
                    acc[q2 * 4 + 2] * sc, acc[q2 * 4 + 3] * sc};
        *(float4*)&op[q2 * 4] = v;
    }
}

// ----------------------------------------------------------------- launch ---
extern "C" void kernel_launch(void* const* d_in, const int* in_sizes, int n_in,
                              void* d_out, int out_size, void* d_ws, size_t ws_size,
                              hipStream_t stream)
{
    const float* x    = (const float*)d_in[0];
    const int*   mask = (const int*)d_in[1];
    const float* Wq   = (const float*)d_in[2];
    const float* bq   = (const float*)d_in[3];
    const float* Wk   = (const float*)d_in[4];
    const float* bk   = (const float*)d_in[5];
    const float* Wv   = (const float*)d_in[6];
    const float* bv   = (const float*)d_in[7];
    float* out = (float*)d_out;

    char* ws = (char*)d_ws;
    __bf16* Qb  = (__bf16*)ws;                        // 4 MiB
    __bf16* Kb  = Qb + (size_t)16384 * 128;           // 4 MiB
    __bf16* Vt  = Kb + (size_t)16384 * 128;           // 4 MiB ([b][h][s])
    __bf16* Wb  = Vt + (size_t)16384 * 128;           // 768 KiB @ 12,582,912
    float*  ml  = (float*)(ws + 12582912);            // 576 KiB, overlays dead Wb
    __bf16* pex = (__bf16*)(ws + 13369344);           // 18 MiB (576 x 32 KiB)

    prep_w<<<384, 256, 0, stream>>>(Wq, Wk, Wv, Wb);
    qkv_gemm<<<768, 256, 0, stream>>>(x, Wb, bq, bk, bv, Qb, Kb, Vt);
    flash_attn<<<576, 512, 0, stream>>>(Qb, Kb, Vt, mask, ml, pex);
    mergeN<<<dim3(32, 4, 4), 256, 0, stream>>>(out, ml, pex);
}